// Round 1
// baseline (2026.690 us; speedup 1.0000x reference)
//
#include <hip/hip_runtime.h>
#include <hip/hip_bf16.h>
#include <stdint.h>

#define N_NODES 16384
#define HDIM 64
#define NM (N_NODES * HDIM)   // 1048576
#define KS 4                  // K-split for the big GEMM
#define BM 128
#define BK 128

typedef __attribute__((ext_vector_type(8))) short short8;
typedef __attribute__((ext_vector_type(16))) float floatx16;

__device__ inline unsigned short f2bf(float x) {
    union { float f; unsigned u; } v; v.f = x;
    unsigned r = v.u + 0x7fff + ((v.u >> 16) & 1);
    return (unsigned short)(r >> 16);
}

// load 8 consecutive fp32 and convert to 8 bf16
__device__ inline short8 cvt8(const float* __restrict__ p) {
    float4 a = *(const float4*)p;
    float4 b = *(const float4*)(p + 4);
    short8 r;
    r[0] = (short)f2bf(a.x); r[1] = (short)f2bf(a.y);
    r[2] = (short)f2bf(a.z); r[3] = (short)f2bf(a.w);
    r[4] = (short)f2bf(b.x); r[5] = (short)f2bf(b.y);
    r[6] = (short)f2bf(b.z); r[7] = (short)f2bf(b.w);
    return r;
}

// ---------------- cast X (fp32) -> bf16 ----------------
__global__ __launch_bounds__(256) void cast_kernel(const float* __restrict__ in,
                                                   unsigned short* __restrict__ out) {
    int i = blockIdx.x * 256 + threadIdx.x;     // over float4s
    float4 v = ((const float4*)in)[i];
    ushort4 o;
    o.x = f2bf(v.x); o.y = f2bf(v.y); o.z = f2bf(v.z); o.w = f2bf(v.w);
    ((ushort4*)out)[i] = o;
}

// ---------------- HrT[f][j] = sum_c W[f][c] * h[j][c]  (store bf16, [64][16384]) ----------------
// grid 128 (128 j per block), block 256 = 4 waves; wave w: j rows [j0, j0+32)
__global__ __launch_bounds__(256) void prep_hrT(const float* __restrict__ W,
                                                const unsigned short* __restrict__ h,
                                                unsigned short* __restrict__ HrT, int Cin) {
    int t = threadIdx.x, lane = t & 63, w = t >> 6;
    int j0 = blockIdx.x * 128 + 32 * w;
    int n = lane & 31, q = lane >> 5;
    floatx16 acc0 = {}, acc1 = {};
    for (int c0 = 0; c0 < Cin; c0 += 16) {
        int k = c0 + 8 * q;
        short8 b  = *(const short8*)(h + (size_t)(j0 + n) * Cin + k); // B[k][n=j]
        short8 a0 = cvt8(W + (size_t)n * Cin + k);                    // A[m=f][k]
        short8 a1 = cvt8(W + (size_t)(n + 32) * Cin + k);
        acc0 = __builtin_amdgcn_mfma_f32_32x32x16_bf16(a0, b, acc0, 0, 0, 0);
        acc1 = __builtin_amdgcn_mfma_f32_32x32x16_bf16(a1, b, acc1, 0, 0, 0);
    }
#pragma unroll
    for (int r = 0; r < 16; ++r) {
        int row = (r & 3) + 8 * (r >> 2) + 4 * q;   // C/D row within 32-tile
        HrT[((size_t)row << 14) + j0 + n]        = f2bf(acc0[r]);
        HrT[((size_t)(row + 32) << 14) + j0 + n] = f2bf(acc1[r]);
    }
}

// ---------------- Root[j][f] = sum_c h[j][c] * Wr[f][c]  (fp32 [16384][64]) ----------------
__global__ __launch_bounds__(256) void prep_root(const unsigned short* __restrict__ h,
                                                 const float* __restrict__ Wr,
                                                 float* __restrict__ Root, int Cin) {
    int t = threadIdx.x, lane = t & 63, w = t >> 6;
    int j0 = blockIdx.x * 128 + 32 * w;
    int n = lane & 31, q = lane >> 5;
    floatx16 acc0 = {}, acc1 = {};
    for (int c0 = 0; c0 < Cin; c0 += 16) {
        int k = c0 + 8 * q;
        short8 a  = *(const short8*)(h + (size_t)(j0 + n) * Cin + k); // A[m=j][k]
        short8 b0 = cvt8(Wr + (size_t)n * Cin + k);                   // B[k][n=f]
        short8 b1 = cvt8(Wr + (size_t)(n + 32) * Cin + k);
        acc0 = __builtin_amdgcn_mfma_f32_32x32x16_bf16(a, b0, acc0, 0, 0, 0);
        acc1 = __builtin_amdgcn_mfma_f32_32x32x16_bf16(a, b1, acc1, 0, 0, 0);
    }
#pragma unroll
    for (int r = 0; r < 16; ++r) {
        int jrow = j0 + (r & 3) + 8 * (r >> 2) + 4 * q;
        Root[(size_t)jrow * HDIM + n]      = acc0[r];
        Root[(size_t)jrow * HDIM + 32 + n] = acc1[r];
    }
}

// ---------------- big GEMM: partial[ks] = adjT(krange) . Hr(krange) ----------------
// grid (128, KS); block 256 = 4 waves; wave w owns m rows [32w,32w+32), all 64 n.
// adj tile transposed into LDS (bf16) with XOR-swizzled granules.
__global__ __launch_bounds__(256, 2) void agg_kernel(const float* __restrict__ adj,
                                                     const unsigned short* __restrict__ HrT,
                                                     float* __restrict__ part) {
    __shared__ unsigned short As[BM * BK];  // elem (m,k) at m*128 + ((k>>3)^(m&7))*8 + (k&7)
    int t = threadIdx.x, lane = t & 63, w = t >> 6;
    int m0 = blockIdx.x * BM;
    int kbeg = blockIdx.y * (N_NODES / KS);
    int kg = t >> 3;        // 0..31
    int mgb = t & 7;
    int n = lane & 31, q = lane >> 5;
    int mrow = 32 * w + (lane & 31);
    int mbase = mrow << 7;
    int msw = mrow & 7;
    const unsigned short* hb0 = HrT + ((size_t)n << 14);
    const unsigned short* hb1 = HrT + ((size_t)(n + 32) << 14);
    floatx16 acc0 = {}, acc1 = {};

    for (int kt = 0; kt < (N_NODES / KS) / BK; ++kt) {
        int kb = kbeg + kt * BK;
        __syncthreads();   // As safe to overwrite
#pragma unroll
        for (int r = 0; r < 4; ++r) {
            int mg = mgb + 8 * r;  // 0..31
            const float* src = adj + (size_t)(kb + 4 * kg) * N_NODES + m0 + 4 * mg;
            float vv[4][4];
#pragma unroll
            for (int rr = 0; rr < 4; ++rr)
                *(float4*)&vv[rr][0] = *(const float4*)(src + (size_t)rr * N_NODES);
#pragma unroll
            for (int i = 0; i < 4; ++i) {
                int m = 4 * mg + i;
                ushort4 o;
                o.x = f2bf(vv[0][i]); o.y = f2bf(vv[1][i]);
                o.z = f2bf(vv[2][i]); o.w = f2bf(vv[3][i]);
                *(ushort4*)&As[(m << 7) + (((kg >> 1) ^ (m & 7)) << 3) + ((kg & 1) << 2)] = o;
            }
        }
        __syncthreads();
#pragma unroll
        for (int s = 0; s < 8; ++s) {
            int g = 2 * s + q;
            short8 a  = *(const short8*)&As[mbase + ((g ^ msw) << 3)];
            short8 b0 = *(const short8*)(hb0 + kb + 16 * s + 8 * q);
            short8 b1 = *(const short8*)(hb1 + kb + 16 * s + 8 * q);
            acc0 = __builtin_amdgcn_mfma_f32_32x32x16_bf16(a, b0, acc0, 0, 0, 0);
            acc1 = __builtin_amdgcn_mfma_f32_32x32x16_bf16(a, b1, acc1, 0, 0, 0);
        }
    }
    float* P = part + (size_t)blockIdx.y * NM;
#pragma unroll
    for (int r = 0; r < 16; ++r) {
        int row = (r & 3) + 8 * (r >> 2) + 4 * q;
        size_t off = (size_t)(m0 + 32 * w + row) * HDIM;
        P[off + n]      = acc0[r];
        P[off + 32 + n] = acc1[r];
    }
}

// ---------------- epilogue: sum partials + Root + bias, relu, write ----------------
__global__ __launch_bounds__(256) void epilogue(const float* __restrict__ part,
                                                const float* __restrict__ Root,
                                                const float* __restrict__ brel,
                                                unsigned short* __restrict__ out_bf,
                                                float* __restrict__ out_f32, int write_f32) {
    int idx = blockIdx.x * 256 + threadIdx.x;
    int f = idx & 63;
    float v = Root[idx] + brel[f];
    v += part[idx] + part[idx + NM] + part[idx + 2 * NM] + part[idx + 3 * NM];
    v = fmaxf(v, 0.f);
    if (write_f32) out_f32[idx] = v;
    else out_bf[idx] = f2bf(v);
}

extern "C" void kernel_launch(void* const* d_in, const int* in_sizes, int n_in,
                              void* d_out, int out_size, void* d_ws, size_t ws_size,
                              hipStream_t stream) {
    const float* X       = (const float*)d_in[0];
    const float* adj     = (const float*)d_in[1];
    const float* W_rel0  = (const float*)d_in[2];
    const float* b_rel0  = (const float*)d_in[3];
    const float* W_root0 = (const float*)d_in[4];
    const float* W_rel1  = (const float*)d_in[5];
    const float* b_rel1  = (const float*)d_in[6];
    const float* W_root1 = (const float*)d_in[7];
    const float* W_rel2  = (const float*)d_in[8];
    const float* b_rel2  = (const float*)d_in[9];
    const float* W_root2 = (const float*)d_in[10];

    // workspace layout (32 MiB total)
    unsigned short* hbfA = (unsigned short*)d_ws;          // 16384*256 bf16 (X; later h2)
    unsigned short* hbfB = hbfA + (size_t)N_NODES * 256;   // 16384*64 bf16 (h1)
    unsigned short* HrT  = hbfB + (size_t)N_NODES * HDIM;  // 64*16384 bf16
    float* Root = (float*)(HrT + (size_t)HDIM * N_NODES);  // 16384*64 fp32
    float* part = Root + (size_t)NM;                       // KS * 16384*64 fp32

    dim3 blk(256);
    // cast X -> bf16
    cast_kernel<<<(N_NODES * 256) / (256 * 4), blk, 0, stream>>>(X, hbfA);

    // ---- layer 0 (Cin = 256) ----
    prep_hrT<<<128, blk, 0, stream>>>(W_rel0, hbfA, HrT, 256);
    prep_root<<<128, blk, 0, stream>>>(hbfA, W_root0, Root, 256);
    agg_kernel<<<dim3(N_NODES / BM, KS), blk, 0, stream>>>(adj, HrT, part);
    epilogue<<<NM / 256, blk, 0, stream>>>(part, Root, b_rel0, hbfB, nullptr, 0);

    // ---- layer 1 (Cin = 64) ----
    prep_hrT<<<128, blk, 0, stream>>>(W_rel1, hbfB, HrT, 64);
    prep_root<<<128, blk, 0, stream>>>(hbfB, W_root1, Root, 64);
    agg_kernel<<<dim3(N_NODES / BM, KS), blk, 0, stream>>>(adj, HrT, part);
    epilogue<<<NM / 256, blk, 0, stream>>>(part, Root, b_rel1, hbfA, nullptr, 0);

    // ---- layer 2 (Cin = 64) ----
    prep_hrT<<<128, blk, 0, stream>>>(W_rel2, hbfA, HrT, 64);
    prep_root<<<128, blk, 0, stream>>>(hbfA, W_root2, Root, 64);
    agg_kernel<<<dim3(N_NODES / BM, KS), blk, 0, stream>>>(adj, HrT, part);
    epilogue<<<NM / 256, blk, 0, stream>>>(part, Root, b_rel2, nullptr, (float*)d_out, 1);
}

// Round 2
// 1786.833 us; speedup vs baseline: 1.1342x; 1.1342x over previous
//
#include <hip/hip_runtime.h>
#include <hip/hip_bf16.h>
#include <stdint.h>

#define N_NODES 16384
#define HDIM 64
#define NM (N_NODES * HDIM)   // 1048576
#define KS 8                  // K-split for the big GEMM
#define BM 128
#define BK 128
#define KRANGE (N_NODES / KS) // 2048
#define NTILES (KRANGE / BK)  // 16

typedef __attribute__((ext_vector_type(8))) short short8;
typedef __attribute__((ext_vector_type(16))) float floatx16;

__device__ inline unsigned short f2bf(float x) {
    union { float f; unsigned u; } v; v.f = x;
    unsigned r = v.u + 0x7fff + ((v.u >> 16) & 1);
    return (unsigned short)(r >> 16);
}

// load 8 consecutive fp32 and convert to 8 bf16
__device__ inline short8 cvt8(const float* __restrict__ p) {
    float4 a = *(const float4*)p;
    float4 b = *(const float4*)(p + 4);
    short8 r;
    r[0] = (short)f2bf(a.x); r[1] = (short)f2bf(a.y);
    r[2] = (short)f2bf(a.z); r[3] = (short)f2bf(a.w);
    r[4] = (short)f2bf(b.x); r[5] = (short)f2bf(b.y);
    r[6] = (short)f2bf(b.z); r[7] = (short)f2bf(b.w);
    return r;
}

// ---------------- cast X (fp32) -> bf16 ----------------
__global__ __launch_bounds__(256) void cast_kernel(const float* __restrict__ in,
                                                   unsigned short* __restrict__ out) {
    int i = blockIdx.x * 256 + threadIdx.x;     // over float4s
    float4 v = ((const float4*)in)[i];
    ushort4 o;
    o.x = f2bf(v.x); o.y = f2bf(v.y); o.z = f2bf(v.z); o.w = f2bf(v.w);
    ((ushort4*)out)[i] = o;
}

// ---------------- HrT2 tiled: element (k, n) at ((k>>3)*64 + n)*8 + (k&7) shorts ----------------
// Hr[k][n] = sum_c W[n][c] * h[k][c];   k = node j, n = feature f
// grid 128 (128 j per block), block 256 = 4 waves; wave w: j rows [j0, j0+32)
__global__ __launch_bounds__(256) void prep_hrT(const float* __restrict__ W,
                                                const unsigned short* __restrict__ h,
                                                unsigned short* __restrict__ HrT2, int Cin) {
    int t = threadIdx.x, lane = t & 63, w = t >> 6;
    int j0 = blockIdx.x * 128 + 32 * w;
    int n = lane & 31, q = lane >> 5;
    floatx16 acc0 = {}, acc1 = {};
    for (int c0 = 0; c0 < Cin; c0 += 16) {
        int k = c0 + 8 * q;
        short8 b  = *(const short8*)(h + (size_t)(j0 + n) * Cin + k); // B[k][n=j]
        short8 a0 = cvt8(W + (size_t)n * Cin + k);                    // A[m=f][k]
        short8 a1 = cvt8(W + (size_t)(n + 32) * Cin + k);
        acc0 = __builtin_amdgcn_mfma_f32_32x32x16_bf16(a0, b, acc0, 0, 0, 0);
        acc1 = __builtin_amdgcn_mfma_f32_32x32x16_bf16(a1, b, acc1, 0, 0, 0);
    }
    int j = j0 + n;
    size_t jb = (size_t)(j >> 3) * 512 + (j & 7);
#pragma unroll
    for (int r = 0; r < 16; ++r) {
        int f = (r & 3) + 8 * (r >> 2) + 4 * q;     // C/D row within 32-tile = feature
        HrT2[jb + (size_t)f * 8]        = f2bf(acc0[r]);
        HrT2[jb + (size_t)(f + 32) * 8] = f2bf(acc1[r]);
    }
}

// ---------------- Root[j][f] = sum_c h[j][c] * Wr[f][c]  (fp32 [16384][64]) ----------------
__global__ __launch_bounds__(256) void prep_root(const unsigned short* __restrict__ h,
                                                 const float* __restrict__ Wr,
                                                 float* __restrict__ Root, int Cin) {
    int t = threadIdx.x, lane = t & 63, w = t >> 6;
    int j0 = blockIdx.x * 128 + 32 * w;
    int n = lane & 31, q = lane >> 5;
    floatx16 acc0 = {}, acc1 = {};
    for (int c0 = 0; c0 < Cin; c0 += 16) {
        int k = c0 + 8 * q;
        short8 a  = *(const short8*)(h + (size_t)(j0 + n) * Cin + k); // A[m=j][k]
        short8 b0 = cvt8(Wr + (size_t)n * Cin + k);                   // B[k][n=f]
        short8 b1 = cvt8(Wr + (size_t)(n + 32) * Cin + k);
        acc0 = __builtin_amdgcn_mfma_f32_32x32x16_bf16(a, b0, acc0, 0, 0, 0);
        acc1 = __builtin_amdgcn_mfma_f32_32x32x16_bf16(a, b1, acc1, 0, 0, 0);
    }
#pragma unroll
    for (int r = 0; r < 16; ++r) {
        int jrow = j0 + (r & 3) + 8 * (r >> 2) + 4 * q;
        Root[(size_t)jrow * HDIM + n]      = acc0[r];
        Root[(size_t)jrow * HDIM + 32 + n] = acc1[r];
    }
}

// ---------------- layer-0 big GEMM: partial[ky] = adjT(krange) . Hr(krange) ----------------
// Also (optionally) writes adj_bf: bf16 transposed adj in MFMA-fragment tiled layout.
// Tile T = bx*128 + (kb>>7); within tile element (m, k) at (k>>3)*1024 + m*8 + (k&7) shorts.
__global__ __launch_bounds__(256, 3) void agg_cvt(const float* __restrict__ adj,
                                                  const unsigned short* __restrict__ HrT2,
                                                  float* __restrict__ part,
                                                  unsigned short* __restrict__ adj_bf,
                                                  int write_copy) {
    __shared__ unsigned short As[BM * BK];  // elem (m,k) at m*128 + ((k>>3)^(m&7))*8 + (k&7)
    int t = threadIdx.x, lane = t & 63, w = t >> 6;
    int m0 = blockIdx.x * BM;
    int kbeg = blockIdx.y * KRANGE;
    int kg = t >> 3;        // 0..31
    int mgb = t & 7;
    int n = lane & 31, q = lane >> 5;
    int mrow = 32 * w + n;
    int mbase = mrow << 7;
    int msw = mrow & 7;
    floatx16 acc0 = {}, acc1 = {};

    for (int kt = 0; kt < NTILES; ++kt) {
        int kb = kbeg + kt * BK;
        __syncthreads();   // As safe to overwrite
#pragma unroll
        for (int r = 0; r < 4; ++r) {
            int mg = mgb + 8 * r;  // 0..31
            const float* src = adj + (size_t)(kb + 4 * kg) * N_NODES + m0 + 4 * mg;
            float vv[4][4];
#pragma unroll
            for (int rr = 0; rr < 4; ++rr)
                *(float4*)&vv[rr][0] = *(const float4*)(src + (size_t)rr * N_NODES);
#pragma unroll
            for (int i = 0; i < 4; ++i) {
                int m = 4 * mg + i;
                ushort4 o;
                o.x = f2bf(vv[0][i]); o.y = f2bf(vv[1][i]);
                o.z = f2bf(vv[2][i]); o.w = f2bf(vv[3][i]);
                *(ushort4*)&As[(m << 7) + (((kg >> 1) ^ (m & 7)) << 3) + ((kg & 1) << 2)] = o;
            }
        }
        __syncthreads();
        const unsigned short* bp = HrT2 + ((size_t)(kb >> 3) << 9);
#pragma unroll
        for (int s = 0; s < 8; ++s) {
            int g = 2 * s + q;
            short8 a  = *(const short8*)&As[mbase + ((g ^ msw) << 3)];
            short8 b0 = *(const short8*)(bp + (size_t)g * 512 + n * 8);
            short8 b1 = *(const short8*)(bp + (size_t)g * 512 + (n + 32) * 8);
            acc0 = __builtin_amdgcn_mfma_f32_32x32x16_bf16(a, b0, acc0, 0, 0, 0);
            acc1 = __builtin_amdgcn_mfma_f32_32x32x16_bf16(a, b1, acc1, 0, 0, 0);
        }
        if (write_copy) {
            unsigned short* dst = adj_bf + ((size_t)(blockIdx.x * 128 + (kb >> 7)) << 14);
#pragma unroll
            for (int p = 0; p < 8; ++p) {
                int I = p * 256 + t;          // 16B chunk index within tile
                int m = I & 127, g = I >> 7;
                short8 v = *(const short8*)&As[(m << 7) + ((g ^ (m & 7)) << 3)];
                *(short8*)(dst + (size_t)I * 8) = v;
            }
        }
    }
    float* P = part + (size_t)blockIdx.y * NM;
#pragma unroll
    for (int r = 0; r < 16; ++r) {
        int row = (r & 3) + 8 * (r >> 2) + 4 * q;
        size_t off = (size_t)(m0 + 32 * w + row) * HDIM;
        P[off + n]      = acc0[r];
        P[off + 32 + n] = acc1[r];
    }
}

// ---------------- layers 1-2 big GEMM: reads pre-transposed bf16 adj, no LDS, no barriers ----------------
__global__ __launch_bounds__(256, 4) void agg_bf(const unsigned short* __restrict__ adj_bf,
                                                 const unsigned short* __restrict__ HrT2,
                                                 float* __restrict__ part) {
    int t = threadIdx.x, lane = t & 63, w = t >> 6;
    int m0 = blockIdx.x * BM;
    int n = lane & 31, q = lane >> 5;
    int mrow = 32 * w + n;
    floatx16 acc0 = {}, acc1 = {};
    for (int kt = 0; kt < NTILES; ++kt) {
        int kb = blockIdx.y * KRANGE + kt * BK;
        const unsigned short* tp = adj_bf + ((size_t)(blockIdx.x * 128 + (kb >> 7)) << 14);
        const unsigned short* bp = HrT2 + ((size_t)(kb >> 3) << 9);
#pragma unroll
        for (int s = 0; s < 8; ++s) {
            int g = 2 * s + q;
            short8 a  = *(const short8*)(tp + (size_t)g * 1024 + mrow * 8);
            short8 b0 = *(const short8*)(bp + (size_t)g * 512 + n * 8);
            short8 b1 = *(const short8*)(bp + (size_t)g * 512 + (n + 32) * 8);
            acc0 = __builtin_amdgcn_mfma_f32_32x32x16_bf16(a, b0, acc0, 0, 0, 0);
            acc1 = __builtin_amdgcn_mfma_f32_32x32x16_bf16(a, b1, acc1, 0, 0, 0);
        }
    }
    float* P = part + (size_t)blockIdx.y * NM;
#pragma unroll
    for (int r = 0; r < 16; ++r) {
        int row = (r & 3) + 8 * (r >> 2) + 4 * q;
        size_t off = (size_t)(m0 + 32 * w + row) * HDIM;
        P[off + n]      = acc0[r];
        P[off + 32 + n] = acc1[r];
    }
}

// ---------------- epilogue: sum partials + Root + bias, relu, write ----------------
__global__ __launch_bounds__(256) void epilogue(const float* __restrict__ part,
                                                const float* __restrict__ Root,
                                                const float* __restrict__ brel,
                                                unsigned short* __restrict__ out_bf,
                                                float* __restrict__ out_f32, int write_f32) {
    int idx = blockIdx.x * 256 + threadIdx.x;
    int f = idx & 63;
    float v = Root[idx] + brel[f];
#pragma unroll
    for (int i = 0; i < KS; ++i) v += part[idx + (size_t)i * NM];
    v = fmaxf(v, 0.f);
    if (write_f32) out_f32[idx] = v;
    else out_bf[idx] = f2bf(v);
}

extern "C" void kernel_launch(void* const* d_in, const int* in_sizes, int n_in,
                              void* d_out, int out_size, void* d_ws, size_t ws_size,
                              hipStream_t stream) {
    const float* X       = (const float*)d_in[0];
    const float* adj     = (const float*)d_in[1];
    const float* W_rel0  = (const float*)d_in[2];
    const float* b_rel0  = (const float*)d_in[3];
    const float* W_root0 = (const float*)d_in[4];
    const float* W_rel1  = (const float*)d_in[5];
    const float* b_rel1  = (const float*)d_in[6];
    const float* W_root1 = (const float*)d_in[7];
    const float* W_rel2  = (const float*)d_in[8];
    const float* b_rel2  = (const float*)d_in[9];
    const float* W_root2 = (const float*)d_in[10];

    // workspace layout
    unsigned short* hbfA = (unsigned short*)d_ws;          // 16384*256 bf16 = 8 MB (X; later h2)
    unsigned short* hbfB = hbfA + (size_t)N_NODES * 256;   // 2 MB (h1)
    unsigned short* HrT2 = hbfB + (size_t)NM;              // 2 MB, tiled layout
    float* Root = (float*)(HrT2 + (size_t)NM);             // 4 MB
    float* part = Root + (size_t)NM;                       // KS * 4 MB = 32 MB
    unsigned short* adj_bf = (unsigned short*)(part + (size_t)KS * NM);  // 512 MB
    size_t need = (size_t)((char*)adj_bf - (char*)d_ws) + (size_t)N_NODES * N_NODES * 2;
    int use_copy = (ws_size >= need) ? 1 : 0;

    dim3 blk(256);
    dim3 agrid(N_NODES / BM, KS);

    cast_kernel<<<(N_NODES * 256) / (256 * 4), blk, 0, stream>>>(X, hbfA);

    // ---- layer 0 (Cin = 256) ----
    prep_hrT<<<128, blk, 0, stream>>>(W_rel0, hbfA, HrT2, 256);
    prep_root<<<128, blk, 0, stream>>>(hbfA, W_root0, Root, 256);
    agg_cvt<<<agrid, blk, 0, stream>>>(adj, HrT2, part, adj_bf, use_copy);
    epilogue<<<NM / 256, blk, 0, stream>>>(part, Root, b_rel0, hbfB, nullptr, 0);

    // ---- layer 1 (Cin = 64) ----
    prep_hrT<<<128, blk, 0, stream>>>(W_rel1, hbfB, HrT2, 64);
    prep_root<<<128, blk, 0, stream>>>(hbfB, W_root1, Root, 64);
    if (use_copy) agg_bf<<<agrid, blk, 0, stream>>>(adj_bf, HrT2, part);
    else          agg_cvt<<<agrid, blk, 0, stream>>>(adj, HrT2, part, adj_bf, 0);
    epilogue<<<NM / 256, blk, 0, stream>>>(part, Root, b_rel1, hbfA, nullptr, 0);

    // ---- layer 2 (Cin = 64) ----
    prep_hrT<<<128, blk, 0, stream>>>(W_rel2, hbfA, HrT2, 64);
    prep_root<<<128, blk, 0, stream>>>(hbfA, W_root2, Root, 64);
    if (use_copy) agg_bf<<<agrid, blk, 0, stream>>>(adj_bf, HrT2, part);
    else          agg_cvt<<<agrid, blk, 0, stream>>>(adj, HrT2, part, adj_bf, 0);
    epilogue<<<NM / 256, blk, 0, stream>>>(part, Root, b_rel2, nullptr, (float*)d_out, 1);
}